// Round 1
// baseline (660.122 us; speedup 1.0000x reference)
//
#include <hip/hip_runtime.h>

// VQ-VAE EMA vector quantizer, MI355X (gfx950).
// inputs:  [16,64,64,64] f32 (b,c,h,w) -> N=65536 positions, d=64
// embedding: [64,1024] f32 (d,K)
// outputs (flat, f32): q_st[4194304], loss[1], indices[65536],
//                      new_embedding[65536], new_cluster_size[1024], new_embed_avg[65536]

#define K 1024
#define D 64
#define NPOS 65536
#define NELEM 4194304
#define DECAYF 0.99f
#define OMDF 0.01f
#define EPSF 1e-5f
#define CCOST 0.25f

#define OFF_Q 0
#define OFF_LOSS 4194304
#define OFF_IDX 4194305
#define OFF_EMB 4259841
#define OFF_NCS 4325377
#define OFF_AVG 4326401

// ws layout (floats): [0]=loss accum, [64..64+1024)=e2, [2048..3072)=counts,
// [4096..4096+65536)=dw [d][K]

__global__ void e2_kernel(const float* __restrict__ E, float* __restrict__ e2) {
    int k = blockIdx.x * blockDim.x + threadIdx.x;
    if (k < K) {
        float s = 0.f;
#pragma unroll
        for (int c = 0; c < D; ++c) {
            float v = E[c * K + k];
            s = fmaf(v, v, s);
        }
        e2[k] = s;
    }
}

__global__ void __launch_bounds__(256) assign_kernel(
    const float* __restrict__ in, const float* __restrict__ E,
    const float* __restrict__ e2, float* __restrict__ out,
    float* __restrict__ counts, float* __restrict__ dw,
    float* __restrict__ loss) {
    int n = blockIdx.x * 256 + threadIdx.x;
    int w = n & 63;
    int h = (n >> 6) & 63;
    int b = n >> 12;
    int base = b * 262144 + h * 64 + w;  // + c*4096 for channel c

    float x[D];
#pragma unroll
    for (int c = 0; c < D; ++c) x[c] = in[base + c * 4096];

    float best = 3.4e38f;
    int bidx = 0;
    // k in chunks of 16: E[c*K + kc + j] is wave-uniform -> scalar loads
    for (int kc = 0; kc < K; kc += 16) {
        float dot[16];
#pragma unroll
        for (int j = 0; j < 16; ++j) dot[j] = 0.f;
#pragma unroll
        for (int c = 0; c < D; ++c) {
#pragma unroll
            for (int j = 0; j < 16; ++j)
                dot[j] = fmaf(x[c], E[c * K + kc + j], dot[j]);
        }
#pragma unroll
        for (int j = 0; j < 16; ++j) {
            float s = fmaf(-2.f, dot[j], e2[kc + j]);
            if (s < best) { best = s; bidx = kc + j; }  // strict < keeps first (matches argmin)
        }
    }

    out[OFF_IDX + n] = (float)bidx;

    float sq = 0.f;
#pragma unroll
    for (int c = 0; c < D; ++c) {
        float q = E[c * K + bidx];
        out[OFF_Q + base + c * 4096] = q;
        float d = q - x[c];
        sq = fmaf(d, d, sq);
        atomicAdd(&dw[c * K + bidx], x[c]);
    }
    atomicAdd(&counts[bidx], 1.0f);

    __shared__ float red[256];
    red[threadIdx.x] = sq;
    __syncthreads();
    for (int s = 128; s > 0; s >>= 1) {
        if (threadIdx.x < s) red[threadIdx.x] += red[threadIdx.x + s];
        __syncthreads();
    }
    if (threadIdx.x == 0) atomicAdd(loss, red[0]);
}

__global__ void __launch_bounds__(1024) ema_kernel(
    const float* __restrict__ cluster_size, const float* __restrict__ embed_avg,
    const float* __restrict__ counts, const float* __restrict__ dw,
    const float* __restrict__ loss, float* __restrict__ out) {
    int k = threadIdx.x;  // 1024
    float ncs = cluster_size[k] * DECAYF + OMDF * counts[k];

    __shared__ float red[1024];
    red[k] = ncs;
    __syncthreads();
    for (int s = 512; s > 0; s >>= 1) {
        if (k < s) red[k] += red[k + s];
        __syncthreads();
    }
    float nsum = red[0];

    float cs = (ncs + EPSF) / (nsum + 1024.f * EPSF) * nsum;
    out[OFF_NCS + k] = ncs;
#pragma unroll
    for (int c = 0; c < D; ++c) {
        float avg = embed_avg[c * K + k] * DECAYF + OMDF * dw[c * K + k];
        out[OFF_AVG + c * K + k] = avg;
        out[OFF_EMB + c * K + k] = avg / cs;
    }
    if (k == 0) out[OFF_LOSS] = CCOST * loss[0] / (float)NELEM;
}

extern "C" void kernel_launch(void* const* d_in, const int* in_sizes, int n_in,
                              void* d_out, int out_size, void* d_ws, size_t ws_size,
                              hipStream_t stream) {
    const float* in = (const float*)d_in[0];
    const float* E = (const float*)d_in[1];
    const float* cluster_size = (const float*)d_in[2];
    const float* embed_avg = (const float*)d_in[3];
    float* out = (float*)d_out;
    float* ws = (float*)d_ws;

    float* loss = ws;          // 1
    float* e2 = ws + 64;       // 1024
    float* counts = ws + 2048; // 1024
    float* dw = ws + 4096;     // 65536

    hipMemsetAsync(loss, 0, sizeof(float), stream);
    hipMemsetAsync(counts, 0, K * sizeof(float), stream);
    hipMemsetAsync(dw, 0, D * K * sizeof(float), stream);

    e2_kernel<<<4, 256, 0, stream>>>(E, e2);
    assign_kernel<<<NPOS / 256, 256, 0, stream>>>(in, E, e2, out, counts, dw, loss);
    ema_kernel<<<1, 1024, 0, stream>>>(cluster_size, embed_avg, counts, dw, loss, out);
}

// Round 2
// 469.088 us; speedup vs baseline: 1.4072x; 1.4072x over previous
//
#include <hip/hip_runtime.h>

// VQ-VAE EMA vector quantizer, MI355X (gfx950).
// inputs:  [16,64,64,64] f32 (b,c,h,w) -> N=65536 positions, d=64
// embedding: [64,1024] f32 (d,K)
// outputs (flat, f32): q_st[4194304], loss[1], indices[65536],
//                      new_embedding[65536], new_cluster_size[1024], new_embed_avg[65536]

#define K 1024
#define D 64
#define NPOS 65536
#define NELEM 4194304
#define DECAYF 0.99f
#define OMDF 0.01f
#define EPSF 1e-5f
#define CCOST 0.25f

#define OFF_Q 0
#define OFF_LOSS 4194304
#define OFF_IDX 4194305
#define OFF_EMB 4259841
#define OFF_NCS 4325377
#define OFF_AVG 4326401

// ws layout (floats): [0]=loss accum, [64..1088)=e2, [2048..3072)=counts,
// [4096..69632)=dw [d][K], [69632..70656)=cs

__global__ void e2_kernel(const float* __restrict__ E, float* __restrict__ e2) {
    int k = blockIdx.x * blockDim.x + threadIdx.x;
    if (k < K) {
        float s = 0.f;
#pragma unroll
        for (int c = 0; c < D; ++c) {
            float v = E[c * K + k];
            s = fmaf(v, v, s);
        }
        e2[k] = s;
    }
}

// Block = 256 threads = 4 waves. Block handles 64 positions (one w-row).
// Wave w computes scores for k in [w*256, (w+1)*256); lane l = position blk*64+l.
// Cross-wave argmin reduction in LDS; epilogue split by channel range per wave.
__global__ void __launch_bounds__(256, 4) assign_kernel(
    const float* __restrict__ in, const float* __restrict__ E,
    const float* __restrict__ e2, float* __restrict__ out,
    float* __restrict__ counts, float* __restrict__ dw,
    float* __restrict__ loss) {
    int tid = threadIdx.x;
    int l = tid & 63;
    int wv = tid >> 6;
    int blk = blockIdx.x;
    int n = blk * 64 + l;
    // n = ((b*64 + h)*64 + w_coord); blk = b*64+h, w_coord = l
    int base = (blk >> 6) * 262144 + (blk & 63) * 64 + l;  // + c*4096 per channel

    float x[D];
#pragma unroll
    for (int c = 0; c < D; ++c) x[c] = in[base + c * 4096];

    // Force wave-uniform k-base so E/e2 indexing stays on the scalar pipe.
    int kbase = __builtin_amdgcn_readfirstlane(wv << 8);
    const float* Ew = E + kbase;
    const float* e2w = e2 + kbase;

    float best = 3.4e38f;
    int bidx = 0;
#pragma unroll 1
    for (int kc = 0; kc < 256; kc += 16) {
        float dot[16];
#pragma unroll
        for (int j = 0; j < 16; ++j) dot[j] = 0.f;
#pragma unroll
        for (int c = 0; c < D; ++c) {
#pragma unroll
            for (int j = 0; j < 16; ++j)
                dot[j] = fmaf(x[c], Ew[c * K + kc + j], dot[j]);
        }
#pragma unroll
        for (int j = 0; j < 16; ++j) {
            float s = fmaf(-2.f, dot[j], e2w[kc + j]);
            if (s < best) { best = s; bidx = kbase + kc + j; }  // strict <: first min wins
        }
    }

    __shared__ float s_best[4][64];
    __shared__ int s_bidx[4][64];
    __shared__ float red[256];
    s_best[wv][l] = best;
    s_bidx[wv][l] = bidx;
    __syncthreads();

    // Final argmin for position l (done redundantly by all 4 waves).
    float fb = s_best[0][l];
    int fi = s_bidx[0][l];
#pragma unroll
    for (int w2 = 1; w2 < 4; ++w2) {
        float v = s_best[w2][l];
        if (v < fb) { fb = v; fi = s_bidx[w2][l]; }  // ascending w2 = ascending k: ties -> lower idx
    }

    // Epilogue: wave wv handles channels [wv*16, wv*16+16) for its lane's position.
    float sq = 0.f;
#pragma unroll
    for (int cc = 0; cc < 16; ++cc) {
        int c = (wv << 4) + cc;
        float q = E[c * K + fi];
        out[OFF_Q + base + c * 4096] = q;
        float d = q - x[c];
        sq = fmaf(d, d, sq);
        atomicAdd(&dw[c * K + fi], x[c]);
    }
    if (wv == 0) {
        out[OFF_IDX + n] = (float)fi;
        atomicAdd(&counts[fi], 1.0f);
    }

    red[tid] = sq;
    __syncthreads();
    for (int s = 128; s > 0; s >>= 1) {
        if (tid < s) red[tid] += red[tid + s];
        __syncthreads();
    }
    if (tid == 0) atomicAdd(loss, red[0]);
}

__global__ void __launch_bounds__(1024) ema_stage1(
    const float* __restrict__ cluster_size, const float* __restrict__ counts,
    const float* __restrict__ loss, float* __restrict__ out,
    float* __restrict__ cs_ws) {
    int k = threadIdx.x;  // 1024
    float ncs = cluster_size[k] * DECAYF + OMDF * counts[k];

    __shared__ float red[1024];
    red[k] = ncs;
    __syncthreads();
    for (int s = 512; s > 0; s >>= 1) {
        if (k < s) red[k] += red[k + s];
        __syncthreads();
    }
    float nsum = red[0];

    out[OFF_NCS + k] = ncs;
    cs_ws[k] = (ncs + EPSF) / (nsum + 1024.f * EPSF) * nsum;
    if (k == 0) out[OFF_LOSS] = CCOST * loss[0] / (float)NELEM;
}

__global__ void __launch_bounds__(256) ema_stage2(
    const float* __restrict__ embed_avg, const float* __restrict__ dw,
    const float* __restrict__ cs_ws, float* __restrict__ out) {
    int i = blockIdx.x * 256 + threadIdx.x;  // D*K = 65536
    int k = i & (K - 1);
    float avg = embed_avg[i] * DECAYF + OMDF * dw[i];
    out[OFF_AVG + i] = avg;
    out[OFF_EMB + i] = avg / cs_ws[k];
}

extern "C" void kernel_launch(void* const* d_in, const int* in_sizes, int n_in,
                              void* d_out, int out_size, void* d_ws, size_t ws_size,
                              hipStream_t stream) {
    const float* in = (const float*)d_in[0];
    const float* E = (const float*)d_in[1];
    const float* cluster_size = (const float*)d_in[2];
    const float* embed_avg = (const float*)d_in[3];
    float* out = (float*)d_out;
    float* ws = (float*)d_ws;

    float* loss = ws;           // 1
    float* e2 = ws + 64;        // 1024
    float* counts = ws + 2048;  // 1024
    float* dw = ws + 4096;      // 65536
    float* cs = ws + 69632;     // 1024

    hipMemsetAsync(loss, 0, sizeof(float), stream);
    hipMemsetAsync(counts, 0, K * sizeof(float), stream);
    hipMemsetAsync(dw, 0, D * K * sizeof(float), stream);

    e2_kernel<<<4, 256, 0, stream>>>(E, e2);
    assign_kernel<<<NPOS / 64, 256, 0, stream>>>(in, E, e2, out, counts, dw, loss);
    ema_stage1<<<1, 1024, 0, stream>>>(cluster_size, counts, loss, out, cs);
    ema_stage2<<<D * K / 256, 256, 0, stream>>>(embed_avg, dw, cs, out);
}